// Round 1
// baseline (204.747 us; speedup 1.0000x reference)
//
#include <hip/hip_runtime.h>
#include <hip/hip_bf16.h>
#include <stdint.h>

#define NN 8192
#define DIN 256
#define HID 128
#define SCALE 0.08838834764831845f  // 1/(sqrt(128)*1.0)

typedef __attribute__((ext_vector_type(8))) short short8;
typedef __attribute__((ext_vector_type(4))) float f32x4;
typedef __attribute__((ext_vector_type(8))) unsigned short u16x8;
typedef __attribute__((ext_vector_type(4))) unsigned short u16x4;

__device__ __forceinline__ unsigned short f2bf(float f) {
  unsigned int u = __builtin_bit_cast(unsigned int, f);
  u += 0x7FFFu + ((u >> 16) & 1u);   // round-to-nearest-even
  return (unsigned short)(u >> 16);
}

__device__ __forceinline__ void async16(const void* g, void* l) {
  __builtin_amdgcn_global_load_lds(
      (const __attribute__((address_space(1))) unsigned int*)g,
      (__attribute__((address_space(3))) unsigned int*)l, 16, 0, 0);
}

// ---------------- Kernel A: messages, q, k, nf->bf16, Wu^T ----------------
__global__ __launch_bounds__(256) void ka(
    const float* __restrict__ nf, const float* __restrict__ msg_w,
    const float* __restrict__ msg_b, const float* __restrict__ qw,
    const float* __restrict__ kw, const float* __restrict__ upd_w,
    unsigned short* __restrict__ q_bf, unsigned short* __restrict__ k_bf,
    unsigned short* __restrict__ m_t, unsigned short* __restrict__ nf_bf,
    unsigned short* __restrict__ w_t) {
  int b = blockIdx.x;
  int t = threadIdx.x;
  if (b == 512) {  // upd_w [384][128] fp32 -> w_t [128][384] bf16
    for (int idx = t; idx < 384 * HID; idx += 256) {
      int j = idx / HID, h = idx % HID;
      w_t[h * 384 + j] = f2bf(upd_w[idx]);
    }
    return;
  }
  __shared__ __align__(16) float nfl[16][DIN];
  __shared__ __align__(16) float ml[16][HID];
  int i0 = b * 16;
  // phase 0: load nf tile -> LDS fp32, write nf_bf
  {
    int row = t >> 4, c0 = (t & 15) * 16;
    const float* srcp = nf + (size_t)(i0 + row) * DIN + c0;
    unsigned short ob[16];
#pragma unroll
    for (int v = 0; v < 4; ++v) {
      f32x4 x = *(const f32x4*)(srcp + v * 4);
      *(f32x4*)&nfl[row][c0 + v * 4] = x;
#pragma unroll
      for (int e = 0; e < 4; ++e) ob[v * 4 + e] = f2bf(x[e]);
    }
    u16x8 o0, o1;
#pragma unroll
    for (int e = 0; e < 8; ++e) { o0[e] = ob[e]; o1[e] = ob[8 + e]; }
    *(u16x8*)(nf_bf + (size_t)(i0 + row) * DIN + c0) = o0;
    *(u16x8*)(nf_bf + (size_t)(i0 + row) * DIN + c0 + 8) = o1;
  }
  __syncthreads();
  int h = t & 127;
  int r0 = t >> 7;  // 0 or 1
  // phase 1: messages
  {
    float accm[8];
#pragma unroll
    for (int rr = 0; rr < 8; ++rr) accm[rr] = 0.f;
    for (int j = 0; j < DIN; ++j) {
      float w = msg_w[j * HID + h];
#pragma unroll
      for (int rr = 0; rr < 8; ++rr) accm[rr] = fmaf(nfl[r0 + rr * 2][j], w, accm[rr]);
    }
    float bias = msg_b[h];
#pragma unroll
    for (int rr = 0; rr < 8; ++rr) ml[r0 + rr * 2][h] = accm[rr] + bias;
  }
  __syncthreads();
  // write m_t (transposed bf16): thread -> h = t>>1, i-block = (t&1)*8
  {
    int hh = t >> 1, i8 = (t & 1) * 8;
    u16x8 o;
#pragma unroll
    for (int v = 0; v < 8; ++v) o[v] = f2bf(ml[i8 + v][hh]);
    *(u16x8*)(m_t + (size_t)hh * NN + i0 + i8) = o;
  }
  // phase 2: q,k
  {
    float accq[8], acck[8];
#pragma unroll
    for (int rr = 0; rr < 8; ++rr) { accq[rr] = 0.f; acck[rr] = 0.f; }
    for (int j = 0; j < HID; ++j) {
      float qv = qw[j * HID + h], kv = kw[j * HID + h];
#pragma unroll
      for (int rr = 0; rr < 8; ++rr) {
        float mv = ml[r0 + rr * 2][j];
        accq[rr] = fmaf(mv, qv, accq[rr]);
        acck[rr] = fmaf(mv, kv, acck[rr]);
      }
    }
#pragma unroll
    for (int rr = 0; rr < 8; ++rr) {
      int r = i0 + r0 + rr * 2;
      q_bf[(size_t)r * HID + h] = f2bf(accq[rr]);
      k_bf[(size_t)r * HID + h] = f2bf(acck[rr]);
    }
  }
}

// ---------------- Kernel B: fused gate + aggregate (flash-style) ----------------
// grid (128, 4): blockIdx.x = 64-row tile, blockIdx.y = 2048-col j-chunk
__global__ __launch_bounds__(256) void kb(
    const unsigned short* __restrict__ q_bf, const unsigned short* __restrict__ k_bf,
    const unsigned short* __restrict__ m_t, const float* __restrict__ adj,
    const float* __restrict__ gate_bias, float* __restrict__ agg_parts) {
  __shared__ __align__(16) char klds[16384];   // k tile [64 rows][128 k] bf16, 16B-blk swizzled
  __shared__ __align__(16) char mlds[16384];   // mT tile [128 h][64 j] bf16, 16B-blk swizzled
  __shared__ __align__(16) char glds[8192];    // gates [4 waves][16][64] bf16, byte-xor swizzled
  int t = threadIdx.x, l = t & 63, w = t >> 6;
  int lr = l & 15, lg = l >> 4;
  int i0 = blockIdx.x * 64;
  int jbase = blockIdx.y * (NN / 4);
  float gb = gate_bias[0];

  // q fragments (held all kernel): wave rows i0 + w*16 .. +15
  int qrow = i0 + w * 16 + lr;
  short8 qf[4];
#pragma unroll
  for (int kk = 0; kk < 4; ++kk)
    qf[kk] = *(const short8*)(q_bf + (size_t)qrow * HID + kk * 32 + lg * 8);

  f32x4 acc[8];
#pragma unroll
  for (int nt = 0; nt < 8; ++nt) acc[nt] = (f32x4){0.f, 0.f, 0.f, 0.f};

  for (int jt = 0; jt < 32; ++jt) {
    int j0 = jbase + jt * 64;
    __syncthreads();  // all waves done reading previous tile
    // stage k tile: linear LDS dest, inverse-swizzled global source
#pragma unroll
    for (int p = 0; p < 4; ++p) {
      int row = p * 16 + (t >> 4);
      int lb = (t & 15) ^ (row & 7);
      async16(k_bf + (size_t)(j0 + row) * HID + lb * 8, klds + p * 4096 + w * 1024);
    }
#pragma unroll
    for (int p = 0; p < 4; ++p) {
      int row = p * 32 + (t >> 3);
      int lb = (t & 7) ^ (row & 7);
      async16(m_t + (size_t)row * NN + j0 + lb * 8, mlds + p * 4096 + w * 1024);
    }
    // adjacency: read once, no reuse -> straight from global
    float adjv[4][4];
#pragma unroll
    for (int jt16 = 0; jt16 < 4; ++jt16)
#pragma unroll
      for (int reg = 0; reg < 4; ++reg)
        adjv[jt16][reg] =
            adj[(size_t)(i0 + w * 16 + lg * 4 + reg) * NN + j0 + jt16 * 16 + lr];
    __syncthreads();  // barrier drains vmcnt -> staged LDS + adj ready

    // S = q @ k^T, then gate = sigmoid(S*scale+gb)*adj -> bf16 into glds
#pragma unroll
    for (int jt16 = 0; jt16 < 4; ++jt16) {
      f32x4 s_acc = (f32x4){0.f, 0.f, 0.f, 0.f};
#pragma unroll
      for (int kk = 0; kk < 4; ++kk) {
        int row = jt16 * 16 + lr;
        int blk = kk * 4 + lg;
        const short8 bf = *(const short8*)(klds + row * 256 + ((blk ^ (row & 7)) * 16));
        s_acc = __builtin_amdgcn_mfma_f32_16x16x32_bf16(qf[kk], bf, s_acc, 0, 0, 0);
      }
#pragma unroll
      for (int reg = 0; reg < 4; ++reg) {
        float x = s_acc[reg] * SCALE + gb;
        float e = __expf(-x);
        float g = adjv[jt16][reg] * __builtin_amdgcn_rcpf(1.0f + e);
        int row = lg * 4 + reg;
        int colb = (jt16 * 16 + lr) * 2;
        *(unsigned short*)(glds + w * 2048 + row * 128 + (colb ^ ((row & 7) << 4))) =
            f2bf(g);
      }
    }
    // PV: acc += P @ m   (A-frag from glds, B-frag from mlds)
#pragma unroll
    for (int kk2 = 0; kk2 < 2; ++kk2) {
      short8 af = *(const short8*)(glds + w * 2048 + lr * 128 +
                                   ((kk2 * 64 + lg * 16) ^ ((lr & 7) << 4)));
#pragma unroll
      for (int nt = 0; nt < 8; ++nt) {
        int mrow = nt * 16 + lr;
        int blk = kk2 * 4 + lg;
        const short8 bf =
            *(const short8*)(mlds + mrow * 128 + ((blk ^ (mrow & 7)) * 16));
        acc[nt] = __builtin_amdgcn_mfma_f32_16x16x32_bf16(af, bf, acc[nt], 0, 0, 0);
      }
    }
  }
  // write partial aggregate (fp32)
  float* part = agg_parts + (size_t)blockIdx.y * NN * HID;
#pragma unroll
  for (int nt = 0; nt < 8; ++nt)
#pragma unroll
    for (int reg = 0; reg < 4; ++reg)
      part[(size_t)(i0 + w * 16 + lg * 4 + reg) * HID + nt * 16 + lr] = acc[nt][reg];
}

// ---------------- Kernel C: update GEMM + ReLU + LayerNorm ----------------
__global__ __launch_bounds__(256) void kc(
    const unsigned short* __restrict__ nf_bf, const float* __restrict__ agg_parts,
    const unsigned short* __restrict__ w_t, const float* __restrict__ upd_b,
    const float* __restrict__ gamma, const float* __restrict__ beta,
    float* __restrict__ out) {
  __shared__ __align__(16) unsigned short aggl[64][136];  // +8 pad: conflict-free frags
  int t = threadIdx.x, l = t & 63, w = t >> 6;
  int i0 = blockIdx.x * 64;
  // phase 0: sum 4 partials -> bf16 tile in LDS
  {
    const f32x4* p0 = (const f32x4*)(agg_parts + (size_t)i0 * HID);
    const size_t ps = (size_t)NN * HID / 4;
    for (int e = t; e < 64 * HID / 4; e += 256) {
      f32x4 s = p0[e] + p0[e + ps] + p0[e + 2 * ps] + p0[e + 3 * ps];
      int row = (e * 4) / HID, col = (e * 4) % HID;
      u16x4 o;
#pragma unroll
      for (int v = 0; v < 4; ++v) o[v] = f2bf(s[v]);
      *(u16x4*)&aggl[row][col] = o;
    }
  }
  __syncthreads();
  int lr = l & 15, lg = l >> 4;
  int arow = i0 + w * 16 + lr;
  short8 af[12];
#pragma unroll
  for (int kk = 0; kk < 8; ++kk)
    af[kk] = *(const short8*)(nf_bf + (size_t)arow * DIN + kk * 32 + lg * 8);
#pragma unroll
  for (int kk = 8; kk < 12; ++kk)
    af[kk] = *(const short8*)(&aggl[w * 16 + lr][(kk - 8) * 32 + lg * 8]);
  f32x4 acc[8];
#pragma unroll
  for (int nt = 0; nt < 8; ++nt) acc[nt] = (f32x4){0.f, 0.f, 0.f, 0.f};
#pragma unroll
  for (int kk = 0; kk < 12; ++kk)
#pragma unroll
    for (int nt = 0; nt < 8; ++nt) {
      const short8 bf =
          *(const short8*)(w_t + (size_t)(nt * 16 + lr) * 384 + kk * 32 + lg * 8);
      acc[nt] = __builtin_amdgcn_mfma_f32_16x16x32_bf16(af[kk], bf, acc[nt], 0, 0, 0);
    }
  // bias + relu + LN (rows lg*4+reg of this wave's 16-row tile)
  float ub[8], ga[8], be[8];
#pragma unroll
  for (int nt = 0; nt < 8; ++nt) {
    ub[nt] = upd_b[nt * 16 + lr];
    ga[nt] = gamma[nt * 16 + lr];
    be[nt] = beta[nt * 16 + lr];
  }
  float v[8][4], sum[4], sq[4];
#pragma unroll
  for (int reg = 0; reg < 4; ++reg) { sum[reg] = 0.f; sq[reg] = 0.f; }
#pragma unroll
  for (int nt = 0; nt < 8; ++nt)
#pragma unroll
    for (int reg = 0; reg < 4; ++reg) {
      float x = acc[nt][reg] + ub[nt];
      x = fmaxf(x, 0.f);
      v[nt][reg] = x;
      sum[reg] += x;
      sq[reg] = fmaf(x, x, sq[reg]);
    }
#pragma unroll
  for (int reg = 0; reg < 4; ++reg) {
#pragma unroll
    for (int m = 1; m < 16; m <<= 1) {
      sum[reg] += __shfl_xor(sum[reg], m, 16);
      sq[reg] += __shfl_xor(sq[reg], m, 16);
    }
  }
#pragma unroll
  for (int reg = 0; reg < 4; ++reg) {
    float mu = sum[reg] * (1.0f / 128.0f);
    float var = sq[reg] * (1.0f / 128.0f) - mu * mu;
    float rstd = rsqrtf(var + 1e-5f);
    int orow = i0 + w * 16 + lg * 4 + reg;
#pragma unroll
    for (int nt = 0; nt < 8; ++nt) {
      float y = (v[nt][reg] - mu) * rstd * ga[nt] + be[nt];
      out[(size_t)orow * HID + nt * 16 + lr] = y;
    }
  }
}

extern "C" void kernel_launch(void* const* d_in, const int* in_sizes, int n_in,
                              void* d_out, int out_size, void* d_ws, size_t ws_size,
                              hipStream_t stream) {
  const float* nf    = (const float*)d_in[0];
  const float* adj   = (const float*)d_in[1];
  const float* msg_w = (const float*)d_in[2];
  const float* msg_b = (const float*)d_in[3];
  const float* upd_w = (const float*)d_in[4];
  const float* upd_b = (const float*)d_in[5];
  const float* qw    = (const float*)d_in[6];
  const float* kw    = (const float*)d_in[7];
  const float* gbias = (const float*)d_in[8];
  const float* gamma = (const float*)d_in[9];
  const float* beta  = (const float*)d_in[10];
  char* ws = (char*)d_ws;
  unsigned short* q_bf  = (unsigned short*)(ws);              // 2 MB
  unsigned short* k_bf  = (unsigned short*)(ws + 0x200000);   // 2 MB
  unsigned short* m_t   = (unsigned short*)(ws + 0x400000);   // 2 MB
  unsigned short* nf_bf = (unsigned short*)(ws + 0x600000);   // 4 MB
  unsigned short* w_t   = (unsigned short*)(ws + 0xA00000);   // 96 KB
  float* agg            = (float*)(ws + 0xA20000);            // 4 x 4 MB

  ka<<<513, 256, 0, stream>>>(nf, msg_w, msg_b, qw, kw, upd_w, q_bf, k_bf, m_t, nf_bf, w_t);
  kb<<<dim3(128, 4), 256, 0, stream>>>(q_bf, k_bf, m_t, adj, gbias, agg);
  kc<<<128, 256, 0, stream>>>(nf_bf, agg, w_t, upd_b, gamma, beta, (float*)d_out);
}

// Round 2
// 137.183 us; speedup vs baseline: 1.4925x; 1.4925x over previous
//
#include <hip/hip_runtime.h>
#include <hip/hip_bf16.h>
#include <stdint.h>

#define NN 8192
#define DIN 256
#define HID 128
#define SCALE 0.08838834764831845f  // 1/(sqrt(128)*1.0)

typedef __attribute__((ext_vector_type(8))) short short8;
typedef __attribute__((ext_vector_type(4))) float f32x4;
typedef __attribute__((ext_vector_type(8))) unsigned short u16x8;
typedef __attribute__((ext_vector_type(4))) unsigned short u16x4;

__device__ __forceinline__ unsigned short f2bf(float f) {
  unsigned int u = __builtin_bit_cast(unsigned int, f);
  u += 0x7FFFu + ((u >> 16) & 1u);   // round-to-nearest-even
  return (unsigned short)(u >> 16);
}

__device__ __forceinline__ void async16(const void* g, void* l) {
  __builtin_amdgcn_global_load_lds(
      (const __attribute__((address_space(1))) unsigned int*)g,
      (__attribute__((address_space(3))) unsigned int*)l, 16, 0, 0);
}

// ---------------- Kernel W: weights -> bf16 transposed ----------------
// mwT[128][256], qwT[128][128], kwT[128][128], w_t[128][384]
__global__ __launch_bounds__(256) void kw0(
    const float* __restrict__ msg_w, const float* __restrict__ qw,
    const float* __restrict__ kw, const float* __restrict__ upd_w,
    unsigned short* __restrict__ mwT, unsigned short* __restrict__ qwT,
    unsigned short* __restrict__ kwT, unsigned short* __restrict__ w_t) {
  int idx0 = blockIdx.x * 1792 + threadIdx.x;
#pragma unroll
  for (int it = 0; it < 7; ++it) {
    int idx = idx0 + it * 256;
    if (idx < 32768) {                       // mwT
      int h = idx >> 8, j = idx & 255;
      mwT[idx] = f2bf(msg_w[j * HID + h]);
    } else if (idx < 49152) {                // qwT
      int r = idx - 32768, h = r >> 7, j = r & 127;
      qwT[r] = f2bf(qw[j * HID + h]);
    } else if (idx < 65536) {                // kwT
      int r = idx - 49152, h = r >> 7, j = r & 127;
      kwT[r] = f2bf(kw[j * HID + h]);
    } else {                                 // w_t
      int r = idx - 65536, h = r / 384, j = r % 384;
      w_t[r] = f2bf(upd_w[j * HID + h]);
    }
  }
}

// ---------------- Kernel A: messages, q, k via MFMA ----------------
// grid 256 blocks x 32 rows. wave w: local rows (w>>1)*16, col-half (w&1)
__global__ __launch_bounds__(256) void ka(
    const float* __restrict__ nf, const unsigned short* __restrict__ mwT,
    const float* __restrict__ msg_b, const unsigned short* __restrict__ qwT,
    const unsigned short* __restrict__ kwT, unsigned short* __restrict__ q_bf,
    unsigned short* __restrict__ k_bf, unsigned short* __restrict__ m_t,
    unsigned short* __restrict__ nf_bf) {
  __shared__ __align__(16) unsigned short nfl[32][264];
  __shared__ __align__(16) unsigned short ml[32][136];
  int t = threadIdx.x, l = t & 63, w = t >> 6;
  int lr = l & 15, lg = l >> 4;
  int i0 = blockIdx.x * 32;
  // phase 0: nf fp32 -> bf16 (LDS + global nf_bf)
  {
    int row = t >> 3, c0 = (t & 7) * 32;
    const float* src = nf + (size_t)(i0 + row) * DIN + c0;
    unsigned short* gdst = nf_bf + (size_t)(i0 + row) * DIN + c0;
#pragma unroll
    for (int v = 0; v < 4; ++v) {
      f32x4 a = *(const f32x4*)(src + v * 8);
      f32x4 b = *(const f32x4*)(src + v * 8 + 4);
      u16x8 o;
#pragma unroll
      for (int e = 0; e < 4; ++e) { o[e] = f2bf(a[e]); o[4 + e] = f2bf(b[e]); }
      *(u16x8*)&nfl[row][c0 + v * 8] = o;
      *(u16x8*)(gdst + v * 8) = o;
    }
  }
  __syncthreads();
  int rl = (w >> 1) * 16;    // local row base
  int nb = (w & 1) * 4;      // nt tile base (of 8)
  // m = nf @ msg_w + b   (K=256)
  f32x4 macc[4];
#pragma unroll
  for (int nt = 0; nt < 4; ++nt) macc[nt] = (f32x4){0.f, 0.f, 0.f, 0.f};
#pragma unroll
  for (int kk = 0; kk < 8; ++kk) {
    short8 af = *(const short8*)&nfl[rl + lr][kk * 32 + lg * 8];
#pragma unroll
    for (int nt = 0; nt < 4; ++nt) {
      short8 bf = *(const short8*)(mwT + (size_t)((nb + nt) * 16 + lr) * DIN + kk * 32 + lg * 8);
      macc[nt] = __builtin_amdgcn_mfma_f32_16x16x32_bf16(af, bf, macc[nt], 0, 0, 0);
    }
  }
#pragma unroll
  for (int nt = 0; nt < 4; ++nt) {
    int col = (nb + nt) * 16 + lr;
    float bias = msg_b[col];
#pragma unroll
    for (int reg = 0; reg < 4; ++reg)
      ml[rl + lg * 4 + reg][col] = f2bf(macc[nt][reg] + bias);
  }
  __syncthreads();
  // m_t writeout (transposed, coalesced 16B)
  {
    int hh = t >> 1, i8 = (t & 1) * 16;
    u16x8 o0, o1;
#pragma unroll
    for (int v = 0; v < 8; ++v) { o0[v] = ml[i8 + v][hh]; o1[v] = ml[i8 + 8 + v][hh]; }
    *(u16x8*)(m_t + (size_t)hh * NN + i0 + i8) = o0;
    *(u16x8*)(m_t + (size_t)hh * NN + i0 + i8 + 8) = o1;
  }
  // q,k = m @ qw / m @ kw   (K=128)
  f32x4 qacc[4], kacc[4];
#pragma unroll
  for (int nt = 0; nt < 4; ++nt) {
    qacc[nt] = (f32x4){0.f, 0.f, 0.f, 0.f};
    kacc[nt] = (f32x4){0.f, 0.f, 0.f, 0.f};
  }
#pragma unroll
  for (int kk = 0; kk < 4; ++kk) {
    short8 af = *(const short8*)&ml[rl + lr][kk * 32 + lg * 8];
#pragma unroll
    for (int nt = 0; nt < 4; ++nt) {
      short8 bq = *(const short8*)(qwT + (size_t)((nb + nt) * 16 + lr) * HID + kk * 32 + lg * 8);
      short8 bk = *(const short8*)(kwT + (size_t)((nb + nt) * 16 + lr) * HID + kk * 32 + lg * 8);
      qacc[nt] = __builtin_amdgcn_mfma_f32_16x16x32_bf16(af, bq, qacc[nt], 0, 0, 0);
      kacc[nt] = __builtin_amdgcn_mfma_f32_16x16x32_bf16(af, bk, kacc[nt], 0, 0, 0);
    }
  }
#pragma unroll
  for (int nt = 0; nt < 4; ++nt) {
    int col = (nb + nt) * 16 + lr;
#pragma unroll
    for (int reg = 0; reg < 4; ++reg) {
      int row = i0 + rl + lg * 4 + reg;
      q_bf[(size_t)row * HID + col] = f2bf(qacc[nt][reg]);
      k_bf[(size_t)row * HID + col] = f2bf(kacc[nt][reg]);
    }
  }
}

// ---------------- Kernel B: fused gate + aggregate (flash-style) ----------------
// grid (128, 8): bx = 64-row tile, by = 1024-col j-chunk; XCD-chunk swizzled
__global__ __launch_bounds__(256, 4) void kb(
    const unsigned short* __restrict__ q_bf, const unsigned short* __restrict__ k_bf,
    const unsigned short* __restrict__ m_t, const float* __restrict__ adj,
    const float* __restrict__ gate_bias, float* __restrict__ agg_parts) {
  __shared__ __align__(16) char klds[16384];   // k tile [64 rows][128 k] bf16, swizzled
  __shared__ __align__(16) char mlds[16384];   // mT tile [128 h][64 j] bf16, swizzled
  __shared__ __align__(16) char glds[8192];    // gates [4 waves][16][64] bf16, swizzled
  int t = threadIdx.x, l = t & 63, w = t >> 6;
  int lr = l & 15, lg = l >> 4;
  // bijective XCD-chunk swizzle: each XCD owns one by-chunk (k/m tiles L2-resident)
  int lin = blockIdx.x + blockIdx.y * 128;
  int nlin = (lin & 7) * 128 + (lin >> 3);
  int bx = nlin & 127, by = nlin >> 7;
  int i0 = bx * 64;
  int jbase = by * 1024;
  float gb = gate_bias[0];

  int qrow = i0 + w * 16 + lr;
  short8 qf[4];
#pragma unroll
  for (int kk = 0; kk < 4; ++kk)
    qf[kk] = *(const short8*)(q_bf + (size_t)qrow * HID + kk * 32 + lg * 8);

  f32x4 acc[8];
#pragma unroll
  for (int nt = 0; nt < 8; ++nt) acc[nt] = (f32x4){0.f, 0.f, 0.f, 0.f};

  for (int jt = 0; jt < 16; ++jt) {
    int j0 = jbase + jt * 64;
    __syncthreads();  // all waves done reading previous tile
    // adjacency first (coldest, longest latency); read once -> no LDS
    float adjv[4][4];
#pragma unroll
    for (int jt16 = 0; jt16 < 4; ++jt16)
#pragma unroll
      for (int reg = 0; reg < 4; ++reg)
        adjv[jt16][reg] =
            adj[(size_t)(i0 + w * 16 + lg * 4 + reg) * NN + j0 + jt16 * 16 + lr];
    // stage k tile: linear LDS dest, inverse-swizzled global source
#pragma unroll
    for (int p = 0; p < 4; ++p) {
      int row = p * 16 + (t >> 4);
      int lb = (t & 15) ^ (row & 7);
      async16(k_bf + (size_t)(j0 + row) * HID + lb * 8, klds + p * 4096 + w * 1024);
    }
#pragma unroll
    for (int p = 0; p < 4; ++p) {
      int row = p * 32 + (t >> 3);
      int lb = (t & 7) ^ (row & 7);
      async16(m_t + (size_t)row * NN + j0 + lb * 8, mlds + p * 4096 + w * 1024);
    }
    __syncthreads();  // drains vmcnt -> staged LDS + adj ready

    // S = q @ k^T ; gate = sigmoid(S*scale+gb)*adj -> bf16 glds
#pragma unroll
    for (int jt16 = 0; jt16 < 4; ++jt16) {
      f32x4 s_acc = (f32x4){0.f, 0.f, 0.f, 0.f};
#pragma unroll
      for (int kk = 0; kk < 4; ++kk) {
        int row = jt16 * 16 + lr;
        int blk = kk * 4 + lg;
        const short8 bf = *(const short8*)(klds + row * 256 + ((blk ^ (row & 7)) * 16));
        s_acc = __builtin_amdgcn_mfma_f32_16x16x32_bf16(qf[kk], bf, s_acc, 0, 0, 0);
      }
#pragma unroll
      for (int reg = 0; reg < 4; ++reg) {
        float x = s_acc[reg] * SCALE + gb;
        float e = __expf(-x);
        float g = adjv[jt16][reg] * __builtin_amdgcn_rcpf(1.0f + e);
        int row = lg * 4 + reg;
        int colb = (jt16 * 16 + lr) * 2;
        *(unsigned short*)(glds + w * 2048 + row * 128 + (colb ^ ((row & 7) << 4))) =
            f2bf(g);
      }
    }
    // PV: acc += P @ m
#pragma unroll
    for (int kk2 = 0; kk2 < 2; ++kk2) {
      short8 af = *(const short8*)(glds + w * 2048 + lr * 128 +
                                   ((kk2 * 64 + lg * 16) ^ ((lr & 7) << 4)));
#pragma unroll
      for (int nt = 0; nt < 8; ++nt) {
        int mrow = nt * 16 + lr;
        int blk = kk2 * 4 + lg;
        const short8 bf =
            *(const short8*)(mlds + mrow * 128 + ((blk ^ (mrow & 7)) * 16));
        acc[nt] = __builtin_amdgcn_mfma_f32_16x16x32_bf16(af, bf, acc[nt], 0, 0, 0);
      }
    }
  }
  float* part = agg_parts + (size_t)by * NN * HID;
#pragma unroll
  for (int nt = 0; nt < 8; ++nt)
#pragma unroll
    for (int reg = 0; reg < 4; ++reg)
      part[(size_t)(i0 + w * 16 + lg * 4 + reg) * HID + nt * 16 + lr] = acc[nt][reg];
}

// ---------------- Kernel C: update GEMM + ReLU + LayerNorm ----------------
__global__ __launch_bounds__(256) void kc(
    const unsigned short* __restrict__ nf_bf, const float* __restrict__ agg_parts,
    const unsigned short* __restrict__ w_t, const float* __restrict__ upd_b,
    const float* __restrict__ gamma, const float* __restrict__ beta,
    float* __restrict__ out) {
  __shared__ __align__(16) unsigned short aggl[64][136];
  int t = threadIdx.x, l = t & 63, w = t >> 6;
  int i0 = blockIdx.x * 64;
  // phase 0: sum 8 partials -> bf16 tile in LDS
  {
    const f32x4* p0 = (const f32x4*)(agg_parts + (size_t)i0 * HID);
    const size_t ps = (size_t)NN * HID / 4;
    for (int e = t; e < 64 * HID / 4; e += 256) {
      f32x4 s = p0[e];
#pragma unroll
      for (int c = 1; c < 8; ++c) s += p0[e + c * ps];
      int row = (e * 4) / HID, col = (e * 4) % HID;
      u16x4 o;
#pragma unroll
      for (int v = 0; v < 4; ++v) o[v] = f2bf(s[v]);
      *(u16x4*)&aggl[row][col] = o;
    }
  }
  __syncthreads();
  int lr = l & 15, lg = l >> 4;
  int arow = i0 + w * 16 + lr;
  short8 af[12];
#pragma unroll
  for (int kk = 0; kk < 8; ++kk)
    af[kk] = *(const short8*)(nf_bf + (size_t)arow * DIN + kk * 32 + lg * 8);
#pragma unroll
  for (int kk = 8; kk < 12; ++kk)
    af[kk] = *(const short8*)(&aggl[w * 16 + lr][(kk - 8) * 32 + lg * 8]);
  f32x4 acc[8];
#pragma unroll
  for (int nt = 0; nt < 8; ++nt) acc[nt] = (f32x4){0.f, 0.f, 0.f, 0.f};
#pragma unroll
  for (int kk = 0; kk < 12; ++kk)
#pragma unroll
    for (int nt = 0; nt < 8; ++nt) {
      const short8 bf =
          *(const short8*)(w_t + (size_t)(nt * 16 + lr) * 384 + kk * 32 + lg * 8);
      acc[nt] = __builtin_amdgcn_mfma_f32_16x16x32_bf16(af[kk], bf, acc[nt], 0, 0, 0);
    }
  float ub[8], ga[8], be[8];
#pragma unroll
  for (int nt = 0; nt < 8; ++nt) {
    ub[nt] = upd_b[nt * 16 + lr];
    ga[nt] = gamma[nt * 16 + lr];
    be[nt] = beta[nt * 16 + lr];
  }
  float v[8][4], sum[4], sq[4];
#pragma unroll
  for (int reg = 0; reg < 4; ++reg) { sum[reg] = 0.f; sq[reg] = 0.f; }
#pragma unroll
  for (int nt = 0; nt < 8; ++nt)
#pragma unroll
    for (int reg = 0; reg < 4; ++reg) {
      float x = acc[nt][reg] + ub[nt];
      x = fmaxf(x, 0.f);
      v[nt][reg] = x;
      sum[reg] += x;
      sq[reg] = fmaf(x, x, sq[reg]);
    }
#pragma unroll
  for (int reg = 0; reg < 4; ++reg) {
#pragma unroll
    for (int m = 1; m < 16; m <<= 1) {
      sum[reg] += __shfl_xor(sum[reg], m, 16);
      sq[reg] += __shfl_xor(sq[reg], m, 16);
    }
  }
#pragma unroll
  for (int reg = 0; reg < 4; ++reg) {
    float mu = sum[reg] * (1.0f / 128.0f);
    float var = sq[reg] * (1.0f / 128.0f) - mu * mu;
    float rstd = rsqrtf(var + 1e-5f);
    int orow = i0 + w * 16 + lg * 4 + reg;
#pragma unroll
    for (int nt = 0; nt < 8; ++nt) {
      float y = (v[nt][reg] - mu) * rstd * ga[nt] + be[nt];
      out[(size_t)orow * HID + nt * 16 + lr] = y;
    }
  }
}

extern "C" void kernel_launch(void* const* d_in, const int* in_sizes, int n_in,
                              void* d_out, int out_size, void* d_ws, size_t ws_size,
                              hipStream_t stream) {
  const float* nf    = (const float*)d_in[0];
  const float* adj   = (const float*)d_in[1];
  const float* msg_w = (const float*)d_in[2];
  const float* msg_b = (const float*)d_in[3];
  const float* upd_w = (const float*)d_in[4];
  const float* upd_b = (const float*)d_in[5];
  const float* qw    = (const float*)d_in[6];
  const float* kw    = (const float*)d_in[7];
  const float* gbias = (const float*)d_in[8];
  const float* gamma = (const float*)d_in[9];
  const float* beta  = (const float*)d_in[10];
  char* ws = (char*)d_ws;
  unsigned short* q_bf  = (unsigned short*)(ws);              // 2 MB
  unsigned short* k_bf  = (unsigned short*)(ws + 0x200000);   // 2 MB
  unsigned short* m_t   = (unsigned short*)(ws + 0x400000);   // 2 MB
  unsigned short* nf_bf = (unsigned short*)(ws + 0x600000);   // 4 MB
  unsigned short* w_t   = (unsigned short*)(ws + 0xA00000);   // 96 KB
  unsigned short* mwT   = (unsigned short*)(ws + 0xA20000);   // 64 KB
  unsigned short* qwT   = (unsigned short*)(ws + 0xA30000);   // 32 KB
  unsigned short* kwT   = (unsigned short*)(ws + 0xA38000);   // 32 KB
  float* agg            = (float*)(ws + 0xA40000);            // 8 x 4 MB

  kw0<<<64, 256, 0, stream>>>(msg_w, qw, kw, upd_w, mwT, qwT, kwT, w_t);
  ka<<<256, 256, 0, stream>>>(nf, mwT, msg_b, qwT, kwT, q_bf, k_bf, m_t, nf_bf);
  kb<<<dim3(128, 8), 256, 0, stream>>>(q_bf, k_bf, m_t, adj, gbias, agg);
  kc<<<128, 256, 0, stream>>>(nf_bf, agg, w_t, upd_b, gamma, beta, (float*)d_out);
}